// Round 15
// baseline (245.891 us; speedup 1.0000x reference)
//
#include <hip/hip_runtime.h>
#include <hip/hip_bf16.h>

// Problem constants
#define NROWS   200000
#define TILE    32                  // rows (n) per block
#define NBLOCKS (NROWS / TILE)      // 6250, exact

typedef __attribute__((ext_vector_type(4))) float f32x4;
typedef __attribute__((ext_vector_type(8))) short bf16x8;

// fp32 pair -> packed bf16x2 (RNE), compiler-lowered packed convert
__device__ __forceinline__ unsigned pk2(float lo, float hi) {
  float2 f{lo, hi};
  __hip_bfloat162 h = __float22bfloat162_rn(f);
  unsigned u;
  __builtin_memcpy(&u, &h, 4);
  return u;
}
// scalar fp32 -> bf16 bits (RNE) — weight prep only (runs once)
__device__ __forceinline__ unsigned short f2bf(float f) {
  unsigned b = __float_as_uint(f);
  b += 0x7fffu + ((b >> 16) & 1u);
  return (unsigned short)(b >> 16);
}
__device__ __forceinline__ float bflo(unsigned pk) { return __uint_as_float(pk << 16); }
__device__ __forceinline__ float bfhi(unsigned pk) { return __uint_as_float(pk & 0xffff0000u); }
__device__ __forceinline__ f32x4 mfma16(bf16x8 a, bf16x8 b, f32x4 c) {
  return __builtin_amdgcn_mfma_f32_16x16x32_bf16(a, b, c, 0, 0, 0);
}
__device__ __forceinline__ float fast_tanh(float x) {
  float e = __expf(2.0f * x);
  return 1.0f - __fdividef(2.0f, e + 1.0f);
}
// LDS XOR swizzles (pure functions of the byte offset -> write/read always
// consistent; preserve 16B alignment). SW for 256B-pitch regions (x, c),
// SW2 for 512B-pitch regions (h1 dbuf, h2 fp32).
__device__ __forceinline__ int SW (int b) { return b ^ (((b >> 8) & 7) << 4); }
__device__ __forceinline__ int SW2(int b) { return b ^ (((b >> 9) & 7) << 4); }

// ---------------------------------------------------------------------------
// Weight prep: W[K][Nout] fp32 -> bf16 MFMA-B fragments.
//   Wp, W1: INTERLEAVED col mapping (col = (nt>>1)*32 + 2*lr + (nt&1)) —
//       waves own tile PAIRS -> lane's 2 cols adjacent -> packed b32 LDS
//       writes (h1 epilogue) / float2 global stores (final).
//   W2: NATURAL mapping (col = nt*16 + lr) — gemm3 waves own single tiles
//       (8 waves x 1 tile = no duplicate frag reads).
// Fragment (kt,nt) at index kt*NT+nt: lane l elem i <- W[kt*32+8*(l>>4)+i][col]
// ---------------------------------------------------------------------------
__global__ void prep_weights(const float* __restrict__ Wp,
                             const float* __restrict__ W1,
                             const float* __restrict__ W2,
                             unsigned short* __restrict__ wpf,
                             unsigned short* __restrict__ w1f,
                             unsigned short* __restrict__ w2f) {
  int t = blockIdx.x * 256 + threadIdx.x;   // 72*256 = 18432 = 288*64
  int q = t >> 6, l = t & 63;
  const float* W; unsigned short* dst; int NT, Nout, qb; bool inter;
  if (q < 32)       { W = Wp; dst = wpf; NT = 8;  Nout = 128; qb = q;       inter = true;  }
  else if (q < 160) { W = W1; dst = w1f; NT = 32; Nout = 512; qb = q - 32;  inter = true;  }
  else              { W = W2; dst = w2f; NT = 8;  Nout = 128; qb = q - 160; inter = false; }
  int kt = qb / NT, nt = qb % NT;
  int row0 = kt * 32 + 8 * (l >> 4);
  int col  = inter ? (nt >> 1) * 32 + 2 * (l & 15) + (nt & 1)
                   : nt * 16 + (l & 15);
  unsigned short v[8];
#pragma unroll
  for (int i = 0; i < 8; ++i) v[i] = f2bf(W[(row0 + i) * Nout + col]);
  uint4 pack;
  pack.x = (unsigned)v[0] | ((unsigned)v[1] << 16);
  pack.y = (unsigned)v[2] | ((unsigned)v[3] << 16);
  pack.z = (unsigned)v[4] | ((unsigned)v[5] << 16);
  pack.w = (unsigned)v[6] | ((unsigned)v[7] << 16);
  *(uint4*)(dst + (size_t)(qb * 64 + l) * 8) = pack;
}

// ---------------------------------------------------------------------------
// Fused kernel (R15 = R12 champion + fp32 h2 + setprio around MFMA):
//  - launch_bounds(512,4): the proven no-spill sweet spot (R13 spilled at 6,
//    R14 showed 5 is unreachable with 8-wave blocks).
//  - h2 kept fp32 in LDS (512B pitch, SW2): removes 8 converts + 24 unpacks
//    per thread and one rounding step.
//  - s_setprio(1) around MFMA clusters (T5: 16 waves/CU at diverse phases).
// LDS = 57344 B:
//   [0,32768):  h1 dbuf (buf0 @0, buf1 @16384), 512B row pitch, SW2.
//               x bf16 [96 rows'=3n+d][128] (256B pitch, SW) lives at
//               [0,24576) until GEMM1 finishes; bar2 fences the overlay.
//   [32768,40960): c bf16 [32][128]  (256B pitch, SW; never overwritten)
//   [40960,57344): h2 fp32 [32][128] (512B pitch, SW2)
// Wave roles:
//   GEMM1/final: m-half h=w>>2 (3 m-tiles) x col-pair p=w&3 (interleaved).
//   gemm2 (chunk of 256 mids): col-pair w of 16 tiles, both m-tiles.
//   gemm3: single col-tile w (natural W2), both m-tiles.
// Schedule (5 barriers):
//   P0 | bar1 | GEMM1 | gemm2(0) | bar2 | epi(0)->buf0; gemm2(1) | bar3 |
//   gemm3(0); epi(1)->buf1 | bar4 | gemm3(1); h2 | bar5 | final.
// ---------------------------------------------------------------------------
__global__ __launch_bounds__(512, 4) void fused_kernel(
    const float* __restrict__ x,
    const float* __restrict__ b1,
    const float* __restrict__ b2,
    const unsigned short* __restrict__ wpf,
    const unsigned short* __restrict__ w1f,
    const unsigned short* __restrict__ w2f,
    float* __restrict__ out) {
  __shared__ __align__(16) char smem[57344];
  const int t = threadIdx.x;   // 0..511
  const int l = t & 63;
  const int w = t >> 6;        // wave id 0..7
  const int lr = l & 15;
  const int lq = l >> 4;
  const int p = w & 3;         // col-pair (GEMM1/final)
  const int h = w >> 2;        // m-half  (GEMM1/final)
  const long n0 = (long)blockIdx.x * TILE;

  // ---- P0: stage x -> bf16 LDS; c = sum_d x^2 in fp32 from un-rounded x.
  // 1024 quad-chunks / 512 threads = 2 each.
#pragma unroll
  for (int k = 0; k < 2; ++k) {
    int pc = t + k * 512, r = pc >> 5, f = (pc & 31) * 4;
    const float* xp = x + (n0 + r) * 384 + f;
    float4 a = *(const float4*)(xp);
    float4 b = *(const float4*)(xp + 128);
    float4 c = *(const float4*)(xp + 256);
    uint2 s0 = { pk2(a.x, a.y), pk2(a.z, a.w) };
    uint2 s1 = { pk2(b.x, b.y), pk2(b.z, b.w) };
    uint2 s2 = { pk2(c.x, c.y), pk2(c.z, c.w) };
    uint2 sc = { pk2(a.x*a.x + b.x*b.x + c.x*c.x,
                     a.y*a.y + b.y*b.y + c.y*c.y),
                 pk2(a.z*a.z + b.z*b.z + c.z*c.z,
                     a.w*a.w + b.w*b.w + c.w*c.w) };
    *(uint2*)(smem + SW((3 * r + 0) * 256 + f * 2)) = s0;
    *(uint2*)(smem + SW((3 * r + 1) * 256 + f * 2)) = s1;
    *(uint2*)(smem + SW((3 * r + 2) * 256 + f * 2)) = s2;
    *(uint2*)(smem + SW(32768 + r * 256 + f * 2))   = sc;
  }
  __syncthreads();   // bar1: x + c visible

  // ---- GEMM1: linx[r'][g], 96x128. Wave: m-half h (rows h*48..h*48+47),
  // col-pair p (interleaved cols 32p+2*lr{,+1} via wpf tiles {2p,2p+1}).
  unsigned lx[3][4];
  {
    f32x4 acc1[3][2] = {};
#pragma unroll
    for (int kt = 0; kt < 4; ++kt) {
      bf16x8 a[3];
#pragma unroll
      for (int m = 0; m < 3; ++m)
        a[m] = *(const bf16x8*)(smem + SW((h * 48 + m * 16 + lr) * 256 + kt * 64 + lq * 16));
      bf16x8 b0 = *(const bf16x8*)(wpf + (size_t)((kt * 8 + 2 * p + 0) * 64 + l) * 8);
      bf16x8 b1_ = *(const bf16x8*)(wpf + (size_t)((kt * 8 + 2 * p + 1) * 64 + l) * 8);
      __builtin_amdgcn_s_setprio(1);
#pragma unroll
      for (int m = 0; m < 3; ++m) acc1[m][0] = mfma16(a[m], b0, acc1[m][0]);
#pragma unroll
      for (int m = 0; m < 3; ++m) acc1[m][1] = mfma16(a[m], b1_, acc1[m][1]);
      __builtin_amdgcn_s_setprio(0);
    }
#pragma unroll
    for (int m = 0; m < 3; ++m)
#pragma unroll
      for (int reg = 0; reg < 4; ++reg)
        lx[m][reg] = pk2(acc1[m][0][reg], acc1[m][1][reg]);
  }

  // ---- MLP in 2 chunks of 256 mids, h1 dbuf @0/@16384 (512B pitch, SW2).
  f32x4 acc2[2][2];
  auto do_gemm2 = [&](int ch) {   // reads stable c + W1 frags only
#pragma unroll
    for (int m = 0; m < 2; ++m)
#pragma unroll
      for (int jj = 0; jj < 2; ++jj) { f32x4 z = {}; acc2[m][jj] = z; }
#pragma unroll
    for (int kt = 0; kt < 4; ++kt) {
      bf16x8 a2[2];
#pragma unroll
      for (int m = 0; m < 2; ++m)
        a2[m] = *(const bf16x8*)(smem + SW(32768 + (m * 16 + lr) * 256 + kt * 64 + lq * 16));
      bf16x8 b0 = *(const bf16x8*)(w1f + (size_t)((kt * 32 + ch * 16 + 2 * w + 0) * 64 + l) * 8);
      bf16x8 b1_ = *(const bf16x8*)(w1f + (size_t)((kt * 32 + ch * 16 + 2 * w + 1) * 64 + l) * 8);
      __builtin_amdgcn_s_setprio(1);
#pragma unroll
      for (int m = 0; m < 2; ++m) acc2[m][0] = mfma16(a2[m], b0, acc2[m][0]);
#pragma unroll
      for (int m = 0; m < 2; ++m) acc2[m][1] = mfma16(a2[m], b1_, acc2[m][1]);
      __builtin_amdgcn_s_setprio(0);
    }
  };
  auto do_epi = [&](int ch) {   // bias + tanh -> packed b32, cols ch*256+w*32+2lr{,+1}
    const int bufb = ch * 16384;
    float2 b1v = *(const float2*)(b1 + ch * 256 + w * 32 + 2 * lr);
#pragma unroll
    for (int m = 0; m < 2; ++m)
#pragma unroll
      for (int reg = 0; reg < 4; ++reg) {
        int row = m * 16 + 4 * lq + reg;
        unsigned pk = pk2(fast_tanh(acc2[m][0][reg] + b1v.x),
                          fast_tanh(acc2[m][1][reg] + b1v.y));
        *(unsigned*)(smem + SW2(bufb + row * 512 + w * 64 + 4 * lr)) = pk;
      }
  };
  f32x4 acc3[2] = {};
  auto do_gemm3 = [&](int ch) {   // single col-tile w (natural W2)
    const int bufb = ch * 16384;
#pragma unroll
    for (int kt = 0; kt < 8; ++kt) {
      bf16x8 b = *(const bf16x8*)(w2f + (size_t)(((ch * 8 + kt) * 8 + w) * 64 + l) * 8);
      bf16x8 a30 = *(const bf16x8*)(smem + SW2(bufb + (0 * 16 + lr) * 512 + kt * 64 + lq * 16));
      bf16x8 a31 = *(const bf16x8*)(smem + SW2(bufb + (1 * 16 + lr) * 512 + kt * 64 + lq * 16));
      __builtin_amdgcn_s_setprio(1);
      acc3[0] = mfma16(a30, b, acc3[0]);
      acc3[1] = mfma16(a31, b, acc3[1]);
      __builtin_amdgcn_s_setprio(0);
    }
  };

  do_gemm2(0);
  __syncthreads();   // bar2: GEMM1's x reads done; h1 bufs (alias x) writable

  do_epi(0);         // -> buf0
  do_gemm2(1);
  __syncthreads();   // bar3: buf0 visible

  do_gemm3(0);       // reads buf0
  do_epi(1);         // -> buf1 (disjoint from buf0; x dead since bar2)
  __syncthreads();   // bar4: buf1 visible

  do_gemm3(1);       // reads buf1

  // ---- h2 = acc3 + b2 -> fp32 @40960 (512B pitch, SW2), col w*16+lr
  {
    float b2v = b2[w * 16 + lr];
#pragma unroll
    for (int m = 0; m < 2; ++m)
#pragma unroll
      for (int reg = 0; reg < 4; ++reg) {
        int row = m * 16 + 4 * lq + reg;
        *(float*)(smem + SW2(40960 + row * 512 + (w * 16 + lr) * 4)) =
            acc3[m][reg] + b2v;
      }
  }
  __syncthreads();   // bar5: h2 visible

  // ---- Final: out[n,d,g] = linx * h2; paired cols 32p+2lr -> float2 h2
  // reads + float2 stores. rp = h*48 + m*16 + 4*lq + reg, n = rp/3.
#pragma unroll
  for (int m = 0; m < 3; ++m)
#pragma unroll
    for (int reg = 0; reg < 4; ++reg) {
      int rp = h * 48 + m * 16 + 4 * lq + reg;
      int n = rp / 3;   // magic-mul
      float2 hp = *(const float2*)(smem + SW2(40960 + n * 512 + (p * 32 + 2 * lr) * 4));
      unsigned pk = lx[m][reg];
      float2 o = { bflo(pk) * hp.x, bfhi(pk) * hp.y };
      *(float2*)(out + n0 * 384 + (long)rp * 128 + p * 32 + 2 * lr) = o;
    }
}

extern "C" void kernel_launch(void* const* d_in, const int* in_sizes, int n_in,
                              void* d_out, int out_size, void* d_ws, size_t ws_size,
                              hipStream_t stream) {
  const float* x  = (const float*)d_in[0];
  const float* Wp = (const float*)d_in[1];
  const float* W1 = (const float*)d_in[2];
  const float* b1 = (const float*)d_in[3];
  const float* W2 = (const float*)d_in[4];
  const float* b2 = (const float*)d_in[5];
  float* out = (float*)d_out;

  // ws layout: W1f [128KB] | W2f [128KB] | Wpf [32KB]
  if (ws_size < 294912) return;
  unsigned short* w1f = (unsigned short*)d_ws;
  unsigned short* w2f = (unsigned short*)((char*)d_ws + 131072);
  unsigned short* wpf = (unsigned short*)((char*)d_ws + 262144);

  prep_weights<<<72, 256, 0, stream>>>(Wp, W1, W2, wpf, w1f, w2f);
  fused_kernel<<<NBLOCKS, 512, 0, stream>>>(x, b1, b2, wpf, w1f, w2f, out);
}

// Round 16
// 197.722 us; speedup vs baseline: 1.2436x; 1.2436x over previous
//
#include <hip/hip_runtime.h>
#include <hip/hip_bf16.h>

// Problem constants
#define NROWS   200000
#define TILE    32                  // rows (n) per block
#define NBLOCKS (NROWS / TILE)      // 6250, exact

typedef __attribute__((ext_vector_type(4))) float f32x4;
typedef __attribute__((ext_vector_type(8))) short bf16x8;

// fp32 pair -> packed bf16x2 (RNE), compiler-lowered packed convert
__device__ __forceinline__ unsigned pk2(float lo, float hi) {
  float2 f{lo, hi};
  __hip_bfloat162 h = __float22bfloat162_rn(f);
  unsigned u;
  __builtin_memcpy(&u, &h, 4);
  return u;
}
// single fp32 -> bf16 bits
__device__ __forceinline__ unsigned short bf1(float v) {
  return (unsigned short)pk2(v, v);
}
// scalar fp32 -> bf16 bits (RNE) — weight prep only (runs once)
__device__ __forceinline__ unsigned short f2bf(float f) {
  unsigned b = __float_as_uint(f);
  b += 0x7fffu + ((b >> 16) & 1u);
  return (unsigned short)(b >> 16);
}
__device__ __forceinline__ float bflo(unsigned pk) { return __uint_as_float(pk << 16); }
__device__ __forceinline__ float bfhi(unsigned pk) { return __uint_as_float(pk & 0xffff0000u); }
__device__ __forceinline__ f32x4 mfma16(bf16x8 a, bf16x8 b, f32x4 c) {
  return __builtin_amdgcn_mfma_f32_16x16x32_bf16(a, b, c, 0, 0, 0);
}
__device__ __forceinline__ float fast_tanh(float x) {
  float e = __expf(2.0f * x);
  return 1.0f - __fdividef(2.0f, e + 1.0f);
}
// LDS XOR swizzles (pure functions of the byte offset -> write/read always
// consistent; preserve 16B alignment). SW for 256B-pitch regions (x, c, h2),
// SW2 for the 512B-pitch h1 chunk buffers.
__device__ __forceinline__ int SW (int b) { return b ^ (((b >> 8) & 7) << 4); }
__device__ __forceinline__ int SW2(int b) { return b ^ (((b >> 9) & 7) << 4); }

// ---------------------------------------------------------------------------
// Weight prep: W[K][Nout] fp32 -> bf16 MFMA-B fragments.
//   Wp, W1: INTERLEAVED col mapping (col = (nt>>1)*32 + 2*lr + (nt&1)) —
//       waves own tile PAIRS -> lane's 2 cols adjacent -> packed b32 LDS
//       writes (h1 epilogue) / float2 global stores (final).
//   W2: NATURAL mapping (col = nt*16 + lr) — gemm3 waves own single tiles
//       (8 waves x 1 tile = no duplicate frag reads).
// Fragment (kt,nt) at index kt*NT+nt: lane l elem i <- W[kt*32+8*(l>>4)+i][col]
// ---------------------------------------------------------------------------
__global__ void prep_weights(const float* __restrict__ Wp,
                             const float* __restrict__ W1,
                             const float* __restrict__ W2,
                             unsigned short* __restrict__ wpf,
                             unsigned short* __restrict__ w1f,
                             unsigned short* __restrict__ w2f) {
  int t = blockIdx.x * 256 + threadIdx.x;   // 72*256 = 18432 = 288*64
  int q = t >> 6, l = t & 63;
  const float* W; unsigned short* dst; int NT, Nout, qb; bool inter;
  if (q < 32)       { W = Wp; dst = wpf; NT = 8;  Nout = 128; qb = q;       inter = true;  }
  else if (q < 160) { W = W1; dst = w1f; NT = 32; Nout = 512; qb = q - 32;  inter = true;  }
  else              { W = W2; dst = w2f; NT = 8;  Nout = 128; qb = q - 160; inter = false; }
  int kt = qb / NT, nt = qb % NT;
  int row0 = kt * 32 + 8 * (l >> 4);
  int col  = inter ? (nt >> 1) * 32 + 2 * (l & 15) + (nt & 1)
                   : nt * 16 + (l & 15);
  unsigned short v[8];
#pragma unroll
  for (int i = 0; i < 8; ++i) v[i] = f2bf(W[(row0 + i) * Nout + col]);
  uint4 pack;
  pack.x = (unsigned)v[0] | ((unsigned)v[1] << 16);
  pack.y = (unsigned)v[2] | ((unsigned)v[3] << 16);
  pack.z = (unsigned)v[4] | ((unsigned)v[5] << 16);
  pack.w = (unsigned)v[6] | ((unsigned)v[7] << 16);
  *(uint4*)(dst + (size_t)(qb * 64 + l) * 8) = pack;
}

// ---------------------------------------------------------------------------
// Fused kernel (R16 = R12 champion, verbatim revert).
// R12: TILE=32 with 512 threads / 8 waves, launch_bounds(512,4).
// = R8's proven-no-spill per-wave register profile (lx 12, acc2 16, acc3 8)
//   + R6's weight L2 traffic (6250 blocks) + 2x R6's occupancy
//   (2 blocks/CU, 16 waves/CU).
// R13 (6 waves/SIMD, 85-reg budget) spilled; R14 (5) unreachable with 8-wave
// blocks; R15 (fp32 h2 + setprio + loop restructure) broke compiler
// scheduling (VALUBusy 56->41). This config is the measured local optimum:
// 198.5 us reported / 211 profiled, WRITE exactly 300 MB, FETCH 152 MB.
// LDS = 49152 B:
//   [0,32768):  h1 dbuf (buf0 @0, buf1 @16384), 512B row pitch, SW2.
//               x bf16 [96 rows'=3n+d][128] (256B pitch, SW) lives at
//               [0,24576) until GEMM1 finishes; bar2 fences the overlay.
//   [32768,40960): c bf16 [32][128]  (256B pitch, SW; never overwritten)
//   [40960,49152): h2 bf16 [32][128] (256B pitch, SW)
// Wave roles:
//   GEMM1/final: m-half h=w>>2 (3 m-tiles) x col-pair p=w&3 (interleaved).
//   gemm2 (chunk of 256 mids): col-pair w of 16 tiles, both m-tiles.
//   gemm3: single col-tile w (natural W2), both m-tiles.
// Schedule (5 barriers):
//   P0 | bar1 | GEMM1 | gemm2(0) | bar2 | epi(0)->buf0; gemm2(1) | bar3 |
//   gemm3(0); epi(1)->buf1 | bar4 | gemm3(1); h2 | bar5 | final.
// ---------------------------------------------------------------------------
__global__ __launch_bounds__(512, 4) void fused_kernel(
    const float* __restrict__ x,
    const float* __restrict__ b1,
    const float* __restrict__ b2,
    const unsigned short* __restrict__ wpf,
    const unsigned short* __restrict__ w1f,
    const unsigned short* __restrict__ w2f,
    float* __restrict__ out) {
  __shared__ __align__(16) char smem[49152];
  const int t = threadIdx.x;   // 0..511
  const int l = t & 63;
  const int w = t >> 6;        // wave id 0..7
  const int lr = l & 15;
  const int lq = l >> 4;
  const int p = w & 3;         // col-pair (GEMM1/final)
  const int h = w >> 2;        // m-half  (GEMM1/final)
  const long n0 = (long)blockIdx.x * TILE;

  // ---- P0: stage x -> bf16 LDS; c = sum_d x^2 in fp32 from un-rounded x.
  // 1024 quad-chunks / 512 threads = 2 each.
#pragma unroll
  for (int k = 0; k < 2; ++k) {
    int pc = t + k * 512, r = pc >> 5, f = (pc & 31) * 4;
    const float* xp = x + (n0 + r) * 384 + f;
    float4 a = *(const float4*)(xp);
    float4 b = *(const float4*)(xp + 128);
    float4 c = *(const float4*)(xp + 256);
    uint2 s0 = { pk2(a.x, a.y), pk2(a.z, a.w) };
    uint2 s1 = { pk2(b.x, b.y), pk2(b.z, b.w) };
    uint2 s2 = { pk2(c.x, c.y), pk2(c.z, c.w) };
    uint2 sc = { pk2(a.x*a.x + b.x*b.x + c.x*c.x,
                     a.y*a.y + b.y*b.y + c.y*c.y),
                 pk2(a.z*a.z + b.z*b.z + c.z*c.z,
                     a.w*a.w + b.w*b.w + c.w*c.w) };
    *(uint2*)(smem + SW((3 * r + 0) * 256 + f * 2)) = s0;
    *(uint2*)(smem + SW((3 * r + 1) * 256 + f * 2)) = s1;
    *(uint2*)(smem + SW((3 * r + 2) * 256 + f * 2)) = s2;
    *(uint2*)(smem + SW(32768 + r * 256 + f * 2))   = sc;
  }
  __syncthreads();   // bar1: x + c visible

  // ---- GEMM1: linx[r'][g], 96x128. Wave: m-half h (rows h*48..h*48+47),
  // col-pair p (interleaved cols 32p+2*lr{,+1} via wpf tiles {2p,2p+1}).
  unsigned lx[3][4];
  {
    f32x4 acc1[3][2] = {};
#pragma unroll
    for (int kt = 0; kt < 4; ++kt) {
      bf16x8 a[3];
#pragma unroll
      for (int m = 0; m < 3; ++m)
        a[m] = *(const bf16x8*)(smem + SW((h * 48 + m * 16 + lr) * 256 + kt * 64 + lq * 16));
#pragma unroll
      for (int jj = 0; jj < 2; ++jj) {
        bf16x8 b = *(const bf16x8*)(wpf + (size_t)((kt * 8 + 2 * p + jj) * 64 + l) * 8);
#pragma unroll
        for (int m = 0; m < 3; ++m) acc1[m][jj] = mfma16(a[m], b, acc1[m][jj]);
      }
    }
#pragma unroll
    for (int m = 0; m < 3; ++m)
#pragma unroll
      for (int reg = 0; reg < 4; ++reg)
        lx[m][reg] = pk2(acc1[m][0][reg], acc1[m][1][reg]);
  }

  // ---- MLP in 2 chunks of 256 mids, h1 dbuf @0/@16384 (512B pitch, SW2).
  f32x4 acc2[2][2];
  auto do_gemm2 = [&](int ch) {   // reads stable c + W1 frags only
#pragma unroll
    for (int m = 0; m < 2; ++m)
#pragma unroll
      for (int jj = 0; jj < 2; ++jj) { f32x4 z = {}; acc2[m][jj] = z; }
#pragma unroll
    for (int kt = 0; kt < 4; ++kt) {
      bf16x8 a2[2];
#pragma unroll
      for (int m = 0; m < 2; ++m)
        a2[m] = *(const bf16x8*)(smem + SW(32768 + (m * 16 + lr) * 256 + kt * 64 + lq * 16));
#pragma unroll
      for (int jj = 0; jj < 2; ++jj) {
        bf16x8 b = *(const bf16x8*)(w1f + (size_t)((kt * 32 + ch * 16 + 2 * w + jj) * 64 + l) * 8);
#pragma unroll
        for (int m = 0; m < 2; ++m) acc2[m][jj] = mfma16(a2[m], b, acc2[m][jj]);
      }
    }
  };
  auto do_epi = [&](int ch) {   // bias + tanh -> packed b32, cols ch*256+w*32+2lr{,+1}
    const int bufb = ch * 16384;
    float2 b1v = *(const float2*)(b1 + ch * 256 + w * 32 + 2 * lr);
#pragma unroll
    for (int m = 0; m < 2; ++m)
#pragma unroll
      for (int reg = 0; reg < 4; ++reg) {
        int row = m * 16 + 4 * lq + reg;
        unsigned pk = pk2(fast_tanh(acc2[m][0][reg] + b1v.x),
                          fast_tanh(acc2[m][1][reg] + b1v.y));
        *(unsigned*)(smem + SW2(bufb + row * 512 + w * 64 + 4 * lr)) = pk;
      }
  };
  f32x4 acc3[2] = {};
  auto do_gemm3 = [&](int ch) {   // single col-tile w (natural W2)
    const int bufb = ch * 16384;
#pragma unroll
    for (int kt = 0; kt < 8; ++kt) {
      bf16x8 b = *(const bf16x8*)(w2f + (size_t)(((ch * 8 + kt) * 8 + w) * 64 + l) * 8);
#pragma unroll
      for (int m = 0; m < 2; ++m) {
        bf16x8 a3 = *(const bf16x8*)(smem + SW2(bufb + (m * 16 + lr) * 512 + kt * 64 + lq * 16));
        acc3[m] = mfma16(a3, b, acc3[m]);
      }
    }
  };

  do_gemm2(0);
  __syncthreads();   // bar2: GEMM1's x reads done; h1 bufs (alias x) writable

  do_epi(0);         // -> buf0
  do_gemm2(1);
  __syncthreads();   // bar3: buf0 visible

  do_gemm3(0);       // reads buf0
  do_epi(1);         // -> buf1 (disjoint from buf0; x dead since bar2)
  __syncthreads();   // bar4: buf1 visible

  do_gemm3(1);       // reads buf1

  // ---- h2 = acc3 + b2 -> bf16 @40960 (fresh region), col w*16+lr
  {
    float b2v = b2[w * 16 + lr];
#pragma unroll
    for (int m = 0; m < 2; ++m)
#pragma unroll
      for (int reg = 0; reg < 4; ++reg) {
        int row = m * 16 + 4 * lq + reg;
        *(unsigned short*)(smem + SW(40960 + row * 256 + (w * 16 + lr) * 2)) =
            bf1(acc3[m][reg] + b2v);
      }
  }
  __syncthreads();   // bar5: h2 visible

  // ---- Final: out[n,d,g] = linx * h2; paired cols 32p+2lr -> b32 h2 reads
  // + float2 stores. rp = h*48 + m*16 + 4*lq + reg, n = rp/3.
#pragma unroll
  for (int m = 0; m < 3; ++m)
#pragma unroll
    for (int reg = 0; reg < 4; ++reg) {
      int rp = h * 48 + m * 16 + 4 * lq + reg;
      int n = rp / 3;   // magic-mul
      unsigned hp = *(const unsigned*)(smem + SW(40960 + n * 256 + p * 64 + 4 * lr));
      unsigned pk = lx[m][reg];
      float2 o = { bflo(pk) * bflo(hp), bfhi(pk) * bfhi(hp) };
      *(float2*)(out + n0 * 384 + (long)rp * 128 + p * 32 + 2 * lr) = o;
    }
}

extern "C" void kernel_launch(void* const* d_in, const int* in_sizes, int n_in,
                              void* d_out, int out_size, void* d_ws, size_t ws_size,
                              hipStream_t stream) {
  const float* x  = (const float*)d_in[0];
  const float* Wp = (const float*)d_in[1];
  const float* W1 = (const float*)d_in[2];
  const float* b1 = (const float*)d_in[3];
  const float* W2 = (const float*)d_in[4];
  const float* b2 = (const float*)d_in[5];
  float* out = (float*)d_out;

  // ws layout: W1f [128KB] | W2f [128KB] | Wpf [32KB]
  if (ws_size < 294912) return;
  unsigned short* w1f = (unsigned short*)d_ws;
  unsigned short* w2f = (unsigned short*)((char*)d_ws + 131072);
  unsigned short* wpf = (unsigned short*)((char*)d_ws + 262144);

  prep_weights<<<72, 256, 0, stream>>>(Wp, W1, W2, wpf, w1f, w2f);
  fused_kernel<<<NBLOCKS, 512, 0, stream>>>(x, b1, b2, wpf, w1f, w2f, out);
}